// Round 1
// baseline (677.230 us; speedup 1.0000x reference)
//
#include <hip/hip_runtime.h>

#define S_LEN 2048
#define DMODEL 2048
#define NHEADS 16
#define DHEAD 128
#define BATCH 2

typedef unsigned short u16;
typedef __attribute__((ext_vector_type(8))) __bf16 bf16x8;
typedef __attribute__((ext_vector_type(4))) float f32x4;

__device__ __forceinline__ u16 f2bf(float f) {
    union { float f; unsigned int u; } a; a.f = f;
    unsigned int u = a.u;
    u += 0x7fffu + ((u >> 16) & 1u);   // RNE
    return (u16)(u >> 16);
}
__device__ __forceinline__ float bf2f(u16 b) {
    union { unsigned int u; float f; } a; a.u = ((unsigned int)b) << 16;
    return a.f;
}

// ---------------- fp32 -> bf16 convert (vectorized x4) ----------------
__global__ void cvt_bf16(const float* __restrict__ in, u16* __restrict__ out, int n4) {
    int i = blockIdx.x * 256 + threadIdx.x;
    if (i >= n4) return;
    f32x4 v = *(const f32x4*)(in + (size_t)i * 4);
    ushort4 o;
    o.x = f2bf(v[0]); o.y = f2bf(v[1]); o.z = f2bf(v[2]); o.w = f2bf(v[3]);
    *(ushort4*)(out + (size_t)i * 4) = o;
}

// ---------------- RoPE in-place on Q and K, layout (B,H,S,Dh) ----------------
__global__ void rope_kernel(u16* __restrict__ Q, u16* __restrict__ K,
                            const float* __restrict__ cosT, const float* __restrict__ sinT) {
    u16* T = blockIdx.z ? K : Q;
    int bh = blockIdx.y;
    int t = blockIdx.x * 256 + threadIdx.x;   // 0 .. S*64-1
    int s = t >> 6;
    int d = t & 63;
    u16* row = T + ((size_t)bh * S_LEN + s) * DHEAD;
    float c  = cosT[s * DHEAD + d];
    float sn = sinT[s * DHEAD + d];           // table duplicated: cos[d]==cos[d+64]
    float q1 = bf2f(row[d]);
    float q2 = bf2f(row[d + 64]);
    row[d]      = f2bf(q1 * c - q2 * sn);
    row[d + 64] = f2bf(q2 * c + q1 * sn);
}

// ---------------- bf16 GEMM: C(M,N) = A(M,K) * W(N,K)^T ----------------
// MODE 1: write bf16, scatter to (B,H,S,Dh)    [Q,K projection]
// MODE 2: write bf16, scatter to (B,H,Dh,S)    [V projection, transposed]
// MODE 3: write fp32 row-major (M,N)           [output projection]
template<int MODE>
__global__ __launch_bounds__(256) void gemm_bt(const u16* __restrict__ A,
                                               const u16* __restrict__ W,
                                               void* __restrict__ out,
                                               int M, int N, int K) {
    __shared__ u16 As[128 * 40];  // 128 rows x 32 k, stride 40 (pad -> 2-way max)
    __shared__ u16 Ws[128 * 40];
    const int tid  = threadIdx.x;
    const int lane = tid & 63;
    const int wave = tid >> 6;
    const int wm = wave >> 1, wn = wave & 1;
    const int col = lane & 15, quad = lane >> 4;
    const int m0 = blockIdx.y * 128, n0 = blockIdx.x * 128;

    f32x4 acc[4][4] = {};

    for (int kk = 0; kk < K; kk += 32) {
        #pragma unroll
        for (int i = 0; i < 2; ++i) {
            int c = tid + i * 256;            // 512 chunks of 8 bf16 per tile
            int row = c >> 2, ko = (c & 3) * 8;
            *(f32x4*)&As[row * 40 + ko] = *(const f32x4*)&A[(size_t)(m0 + row) * K + kk + ko];
            *(f32x4*)&Ws[row * 40 + ko] = *(const f32x4*)&W[(size_t)(n0 + row) * K + kk + ko];
        }
        __syncthreads();
        bf16x8 af[4], wf[4];
        #pragma unroll
        for (int mi = 0; mi < 4; ++mi)
            af[mi] = *(const bf16x8*)&As[(wm * 64 + mi * 16 + col) * 40 + quad * 8];
        #pragma unroll
        for (int ni = 0; ni < 4; ++ni)
            wf[ni] = *(const bf16x8*)&Ws[(wn * 64 + ni * 16 + col) * 40 + quad * 8];
        #pragma unroll
        for (int mi = 0; mi < 4; ++mi)
            #pragma unroll
            for (int ni = 0; ni < 4; ++ni)
                acc[mi][ni] = __builtin_amdgcn_mfma_f32_16x16x32_bf16(af[mi], wf[ni], acc[mi][ni], 0, 0, 0);
        __syncthreads();
    }

    #pragma unroll
    for (int mi = 0; mi < 4; ++mi) {
        #pragma unroll
        for (int ni = 0; ni < 4; ++ni) {
            #pragma unroll
            for (int r = 0; r < 4; ++r) {
                int row  = m0 + wm * 64 + mi * 16 + quad * 4 + r;
                int ncol = n0 + wn * 64 + ni * 16 + col;
                float v = acc[mi][ni][r];
                if (MODE == 3) {
                    ((float*)out)[(size_t)row * N + ncol] = v;
                } else {
                    int b = row >> 11, s = row & 2047;   // S=2048
                    int h = ncol >> 7, d = ncol & 127;   // Dh=128
                    if (MODE == 1)
                        ((u16*)out)[(((size_t)(b * NHEADS + h)) * S_LEN + s) * DHEAD + d] = f2bf(v);
                    else
                        ((u16*)out)[(((size_t)(b * NHEADS + h)) * DHEAD + d) * S_LEN + s] = f2bf(v);
                }
            }
        }
    }
}

// ---------------- causal flash attention ----------------
// Q,K: (B,H,S,Dh) bf16 (post-RoPE).  Vt: (B,H,Dh,S) bf16.
// Out: (B,S,H*Dh) bf16.  Block = 4 waves, 64 q-rows; K-chunks of 32.
__global__ __launch_bounds__(256) void attn_kernel(const u16* __restrict__ Q,
                                                   const u16* __restrict__ K,
                                                   const u16* __restrict__ Vt,
                                                   u16* __restrict__ Ao) {
    __shared__ u16 Ks[32 * 136];    // 32 keys x 128 d, stride 136
    __shared__ u16 Vs[128 * 40];    // 128 d x 32 keys, stride 40
    __shared__ u16 Ps[4][16 * 40];  // per-wave P tile, 16 q x 32 keys, stride 40

    const int tid  = threadIdx.x;
    const int lane = tid & 63;
    const int wave = tid >> 6;
    const int col = lane & 15, quad = lane >> 4;
    const int bh = blockIdx.y;
    const int b = bh >> 4, h = bh & 15;
    const int qb = blockIdx.x * 64;
    const int qw = qb + wave * 16;

    const u16* Qb = Q  + (size_t)bh * S_LEN * DHEAD;
    const u16* Kb = K  + (size_t)bh * S_LEN * DHEAD;
    const u16* Vb = Vt + (size_t)bh * DHEAD * S_LEN;

    bf16x8 qf[4];
    #pragma unroll
    for (int dc = 0; dc < 4; ++dc)
        qf[dc] = *(const bf16x8*)&Qb[(size_t)(qw + col) * DHEAD + dc * 32 + quad * 8];

    f32x4 accO[8] = {};
    float mrow[4], lrow[4];
    #pragma unroll
    for (int r = 0; r < 4; ++r) { mrow[r] = -1e30f; lrow[r] = 0.0f; }
    const float scale = 0.08838834764831845f;  // 1/sqrt(128)

    const int kend = qb + 64;
    for (int kb = 0; kb < kend; kb += 32) {
        // stage K chunk (32x128) and V chunk (128x32)
        #pragma unroll
        for (int i = 0; i < 2; ++i) {
            int c = tid + i * 256;
            int kr = c >> 4, ko = (c & 15) * 8;
            *(f32x4*)&Ks[kr * 136 + ko] = *(const f32x4*)&Kb[(size_t)(kb + kr) * DHEAD + ko];
            int vr = c >> 2, vo = (c & 3) * 8;
            *(f32x4*)&Vs[vr * 40 + vo] = *(const f32x4*)&Vb[(size_t)vr * S_LEN + kb + vo];
        }
        __syncthreads();

        if (kb <= qw + 15) {   // wave-uniform causal skip
            // scores: 16 q x 32 keys (two 16x16 C tiles)
            f32x4 sc[2] = {};
            #pragma unroll
            for (int t = 0; t < 2; ++t)
                #pragma unroll
                for (int dc = 0; dc < 4; ++dc) {
                    bf16x8 kf = *(const bf16x8*)&Ks[(t * 16 + col) * 136 + dc * 32 + quad * 8];
                    sc[t] = __builtin_amdgcn_mfma_f32_16x16x32_bf16(qf[dc], kf, sc[t], 0, 0, 0);
                }

            float pv[2][4], alpha[4];
            #pragma unroll
            for (int r = 0; r < 4; ++r) {
                int q_g = qw + quad * 4 + r;
                float s0 = sc[0][r] * scale;
                float s1 = sc[1][r] * scale;
                if (kb + col > q_g)      s0 = -1e30f;
                if (kb + 16 + col > q_g) s1 = -1e30f;
                float mx = fmaxf(s0, s1);
                mx = fmaxf(mx, __shfl_xor(mx, 1));
                mx = fmaxf(mx, __shfl_xor(mx, 2));
                mx = fmaxf(mx, __shfl_xor(mx, 4));
                mx = fmaxf(mx, __shfl_xor(mx, 8));
                float mn = fmaxf(mrow[r], mx);
                float al = __expf(mrow[r] - mn);
                float p0 = __expf(s0 - mn);
                float p1 = __expf(s1 - mn);
                float rs = p0 + p1;
                rs += __shfl_xor(rs, 1);
                rs += __shfl_xor(rs, 2);
                rs += __shfl_xor(rs, 4);
                rs += __shfl_xor(rs, 8);
                lrow[r] = lrow[r] * al + rs;
                mrow[r] = mn;
                alpha[r] = al;
                pv[0][r] = p0; pv[1][r] = p1;
            }
            #pragma unroll
            for (int ni = 0; ni < 8; ++ni)
                #pragma unroll
                for (int r = 0; r < 4; ++r)
                    accO[ni][r] *= alpha[r];

            // P: C-layout -> A-layout via per-wave LDS round-trip
            u16* P = Ps[wave];
            #pragma unroll
            for (int t = 0; t < 2; ++t)
                #pragma unroll
                for (int r = 0; r < 4; ++r)
                    P[(quad * 4 + r) * 40 + t * 16 + col] = f2bf(pv[t][r]);
            asm volatile("s_waitcnt lgkmcnt(0)" ::: "memory");
            bf16x8 pf = *(const bf16x8*)&P[col * 40 + quad * 8];

            #pragma unroll
            for (int ni = 0; ni < 8; ++ni) {
                bf16x8 vf = *(const bf16x8*)&Vs[(ni * 16 + col) * 40 + quad * 8];
                accO[ni] = __builtin_amdgcn_mfma_f32_16x16x32_bf16(pf, vf, accO[ni], 0, 0, 0);
            }
        }
        __syncthreads();
    }

    // epilogue: O / l, write (B,S,H*Dh) bf16
    #pragma unroll
    for (int ni = 0; ni < 8; ++ni)
        #pragma unroll
        for (int r = 0; r < 4; ++r) {
            int q_g = qw + quad * 4 + r;
            int d = ni * 16 + col;
            float v = accO[ni][r] / lrow[r];
            Ao[((size_t)(b * S_LEN + q_g)) * DMODEL + h * DHEAD + d] = f2bf(v);
        }
}

extern "C" void kernel_launch(void* const* d_in, const int* in_sizes, int n_in,
                              void* d_out, int out_size, void* d_ws, size_t ws_size,
                              hipStream_t stream) {
    const float* x    = (const float*)d_in[0];
    const float* cosT = (const float*)d_in[1];
    const float* sinT = (const float*)d_in[2];
    const float* Wq   = (const float*)d_in[3];
    const float* Wk   = (const float*)d_in[4];
    const float* Wv   = (const float*)d_in[5];
    const float* Wo   = (const float*)d_in[6];

    char* ws = (char*)d_ws;
    size_t off = 0;
    auto carve = [&](size_t bytes) {
        void* p = ws + off;
        off += (bytes + 255) & ~(size_t)255;
        return p;
    };
    const size_t xN = (size_t)BATCH * S_LEN * DMODEL;      // 8388608
    const size_t wN = (size_t)DMODEL * DMODEL;             // 4194304
    u16* xb  = (u16*)carve(xN * 2);
    u16* wqb = (u16*)carve(wN * 2);
    u16* wkb = (u16*)carve(wN * 2);
    u16* wvb = (u16*)carve(wN * 2);
    u16* wob = (u16*)carve(wN * 2);
    u16* Qb  = (u16*)carve(xN * 2);
    u16* Kb  = (u16*)carve(xN * 2);
    u16* Vtb = (u16*)carve(xN * 2);
    u16* attn = xb;   // alias: xb dead after V projection; attention writes after.

    // converts
    cvt_bf16<<<(int)(xN / 4 / 256), 256, 0, stream>>>(x,  xb,  (int)(xN / 4));
    cvt_bf16<<<(int)(wN / 4 / 256), 256, 0, stream>>>(Wq, wqb, (int)(wN / 4));
    cvt_bf16<<<(int)(wN / 4 / 256), 256, 0, stream>>>(Wk, wkb, (int)(wN / 4));
    cvt_bf16<<<(int)(wN / 4 / 256), 256, 0, stream>>>(Wv, wvb, (int)(wN / 4));
    cvt_bf16<<<(int)(wN / 4 / 256), 256, 0, stream>>>(Wo, wob, (int)(wN / 4));

    const int M = BATCH * S_LEN;   // 4096
    dim3 ggrid(DMODEL / 128, M / 128);   // (16, 32)
    gemm_bt<1><<<ggrid, 256, 0, stream>>>(xb, wqb, Qb,  M, DMODEL, DMODEL);
    gemm_bt<1><<<ggrid, 256, 0, stream>>>(xb, wkb, Kb,  M, DMODEL, DMODEL);
    gemm_bt<2><<<ggrid, 256, 0, stream>>>(xb, wvb, Vtb, M, DMODEL, DMODEL);

    rope_kernel<<<dim3(S_LEN * 64 / 256, BATCH * NHEADS, 2), 256, 0, stream>>>(Qb, Kb, cosT, sinT);

    attn_kernel<<<dim3(S_LEN / 64, BATCH * NHEADS), 256, 0, stream>>>(Qb, Kb, Vtb, attn);

    gemm_bt<3><<<ggrid, 256, 0, stream>>>(attn, wob, d_out, M, DMODEL, DMODEL);
}

// Round 2
// 518.651 us; speedup vs baseline: 1.3058x; 1.3058x over previous
//
#include <hip/hip_runtime.h>

#define S_LEN 2048
#define DMODEL 2048
#define NHEADS 16
#define DHEAD 128
#define BATCH 2

typedef unsigned short u16;
typedef __attribute__((ext_vector_type(8))) __bf16 bf16x8;
typedef __attribute__((ext_vector_type(4))) float f32x4;

__device__ __forceinline__ u16 f2bf(float f) {
    union { float f; unsigned int u; } a; a.f = f;
    unsigned int u = a.u;
    u += 0x7fffu + ((u >> 16) & 1u);   // RNE
    return (u16)(u >> 16);
}
__device__ __forceinline__ float bf2f(u16 b) {
    union { unsigned int u; float f; } a; a.u = ((unsigned int)b) << 16;
    return a.f;
}

// async global->LDS, 16B per lane; lds base must be wave-uniform (lane scatter is +lane*16)
__device__ __forceinline__ void g2l16(const void* g, void* l) {
    __builtin_amdgcn_global_load_lds((const __attribute__((address_space(1))) unsigned int*)g,
                                     (__attribute__((address_space(3))) unsigned int*)l,
                                     16, 0, 0);
}

// ---------------- fp32 -> bf16 convert (vectorized x4) ----------------
__global__ void cvt_bf16(const float* __restrict__ in, u16* __restrict__ out, int n4) {
    int i = blockIdx.x * 256 + threadIdx.x;
    if (i >= n4) return;
    f32x4 v = *(const f32x4*)(in + (size_t)i * 4);
    ushort4 o;
    o.x = f2bf(v[0]); o.y = f2bf(v[1]); o.z = f2bf(v[2]); o.w = f2bf(v[3]);
    *(ushort4*)(out + (size_t)i * 4) = o;
}

// ---------------- RoPE in-place on Q and K, layout (B,H,S,Dh) ----------------
__global__ void rope_kernel(u16* __restrict__ Q, u16* __restrict__ K,
                            const float* __restrict__ cosT, const float* __restrict__ sinT) {
    u16* T = blockIdx.z ? K : Q;
    int bh = blockIdx.y;
    int t = blockIdx.x * 256 + threadIdx.x;   // 0 .. S*64-1
    int s = t >> 6;
    int d = t & 63;
    u16* row = T + ((size_t)bh * S_LEN + s) * DHEAD;
    float c  = cosT[s * DHEAD + d];
    float sn = sinT[s * DHEAD + d];           // table duplicated: cos[d]==cos[d+64]
    float q1 = bf2f(row[d]);
    float q2 = bf2f(row[d + 64]);
    row[d]      = f2bf(q1 * c - q2 * sn);
    row[d + 64] = f2bf(q2 * c + q1 * sn);
}

// ---------------- bf16 GEMM: C(M,N) = A(M,K) * W(N,K)^T ----------------
// m97 recipe: 128x128 tile, BK=32, global_load_lds width 16, unpadded stride-32 LDS.
// (frag read bank starts = ((row&1)*16 + quad*4) -> even 8/bank = b128 floor)
// MODE 1: write bf16, scatter to (B,H,S,Dh)    [Q,K projection]
// MODE 2: write bf16, scatter to (B,H,Dh,S)    [V projection, transposed; ushort4 packed]
// MODE 3: write fp32 row-major (M,N)           [output projection]
template<int MODE>
__global__ __launch_bounds__(256) void gemm_bt(const u16* __restrict__ A,
                                               const u16* __restrict__ W,
                                               void* __restrict__ out,
                                               int M, int N, int K) {
    __shared__ u16 As[128 * 32];
    __shared__ u16 Ws[128 * 32];
    const int tid  = threadIdx.x;
    const int lane = tid & 63;
    const int wave = tid >> 6;
    const int wm = wave >> 1, wn = wave & 1;
    const int col = lane & 15, quad = lane >> 4;
    const int m0 = blockIdx.y * 128, n0 = blockIdx.x * 128;

    f32x4 acc[4][4] = {};

    for (int kk = 0; kk < K; kk += 32) {
        #pragma unroll
        for (int i = 0; i < 2; ++i) {
            int c = i * 256 + tid;                 // chunk = 16B = 8 bf16; 512 chunks/array
            int row = c >> 2, ko = (c & 3) * 8;    // 128 rows x 4 chunks
            int cb = i * 256 + wave * 64;          // wave-uniform lds chunk base
            g2l16(A + (size_t)(m0 + row) * K + kk + ko, (void*)(As + cb * 8));
            g2l16(W + (size_t)(n0 + row) * K + kk + ko, (void*)(Ws + cb * 8));
        }
        __syncthreads();
        bf16x8 af[4], wf[4];
        #pragma unroll
        for (int mi = 0; mi < 4; ++mi)
            af[mi] = *(const bf16x8*)&As[(wm * 64 + mi * 16 + col) * 32 + quad * 8];
        #pragma unroll
        for (int ni = 0; ni < 4; ++ni)
            wf[ni] = *(const bf16x8*)&Ws[(wn * 64 + ni * 16 + col) * 32 + quad * 8];
        #pragma unroll
        for (int mi = 0; mi < 4; ++mi)
            #pragma unroll
            for (int ni = 0; ni < 4; ++ni)
                acc[mi][ni] = __builtin_amdgcn_mfma_f32_16x16x32_bf16(af[mi], wf[ni], acc[mi][ni], 0, 0, 0);
        __syncthreads();
    }

    if (MODE == 2) {
        // pack 4 consecutive s (the r index) into one 8B store
        #pragma unroll
        for (int mi = 0; mi < 4; ++mi) {
            #pragma unroll
            for (int ni = 0; ni < 4; ++ni) {
                int s0   = m0 + wm * 64 + mi * 16 + quad * 4;
                int ncol = n0 + wn * 64 + ni * 16 + col;
                int b = s0 >> 11, s = s0 & 2047;
                int h = ncol >> 7, d = ncol & 127;
                ushort4 o;
                o.x = f2bf(acc[mi][ni][0]); o.y = f2bf(acc[mi][ni][1]);
                o.z = f2bf(acc[mi][ni][2]); o.w = f2bf(acc[mi][ni][3]);
                *(ushort4*)&((u16*)out)[(((size_t)(b * NHEADS + h)) * DHEAD + d) * S_LEN + s] = o;
            }
        }
    } else {
        #pragma unroll
        for (int mi = 0; mi < 4; ++mi)
            #pragma unroll
            for (int ni = 0; ni < 4; ++ni)
                #pragma unroll
                for (int r = 0; r < 4; ++r) {
                    int row  = m0 + wm * 64 + mi * 16 + quad * 4 + r;
                    int ncol = n0 + wn * 64 + ni * 16 + col;
                    float v = acc[mi][ni][r];
                    if (MODE == 3) {
                        ((float*)out)[(size_t)row * N + ncol] = v;
                    } else {
                        int b = row >> 11, s = row & 2047;
                        int h = ncol >> 7, d = ncol & 127;
                        ((u16*)out)[(((size_t)(b * NHEADS + h)) * S_LEN + s) * DHEAD + d] = f2bf(v);
                    }
                }
    }
}

// ---------------- causal flash attention ----------------
// Q,K: (B,H,S,Dh) bf16 (post-RoPE).  Vt: (B,H,Dh,S) bf16.  Out: (B,S,H*Dh) bf16.
// Block = 4 waves, processes the PAIR of 64-row q-tiles (pi, 31-pi) sequentially
// -> uniform 66 chunk-iters per block.  blockIdx%8 clusters 4 bh per XCD so the
// K+V working set per XCD (~4MB) fits L2.
__global__ __launch_bounds__(256) void attn_kernel(const u16* __restrict__ Q,
                                                   const u16* __restrict__ K,
                                                   const u16* __restrict__ Vt,
                                                   u16* __restrict__ Ao) {
    __shared__ u16 Ks[32 * 136];    // 32 keys x 128 d, stride 136
    __shared__ u16 Vs[128 * 40];    // 128 d x 32 keys, stride 40
    __shared__ u16 Ps[4][16 * 40];  // per-wave P tile, 16 q x 32 keys, stride 40

    const int tid  = threadIdx.x;
    const int lane = tid & 63;
    const int wave = tid >> 6;
    const int col = lane & 15, quad = lane >> 4;
    const int xcd  = blockIdx.x & 7;
    const int slot = blockIdx.x >> 3;         // [0,64)
    const int bh   = xcd * 4 + (slot & 3);    // 4 heads per XCD
    const int pi   = slot >> 2;               // pair index [0,16)
    const int b = bh >> 4, h = bh & 15;

    const u16* Qb = Q  + (size_t)bh * S_LEN * DHEAD;
    const u16* Kb = K  + (size_t)bh * S_LEN * DHEAD;
    const u16* Vb = Vt + (size_t)bh * DHEAD * S_LEN;
    const float scale = 0.08838834764831845f;  // 1/sqrt(128)

    for (int half = 0; half < 2; ++half) {
        const int qb = (half ? (31 - pi) : pi) * 64;
        const int qw = qb + wave * 16;

        bf16x8 qf[4];
        #pragma unroll
        for (int dc = 0; dc < 4; ++dc)
            qf[dc] = *(const bf16x8*)&Qb[(size_t)(qw + col) * DHEAD + dc * 32 + quad * 8];

        f32x4 accO[8] = {};
        float mrow[4], lrow[4];
        #pragma unroll
        for (int r = 0; r < 4; ++r) { mrow[r] = -1e30f; lrow[r] = 0.0f; }

        const int kend = qb + 64;
        for (int kb = 0; kb < kend; kb += 32) {
            #pragma unroll
            for (int i = 0; i < 2; ++i) {
                int c = tid + i * 256;
                int kr = c >> 4, ko = (c & 15) * 8;
                *(f32x4*)&Ks[kr * 136 + ko] = *(const f32x4*)&Kb[(size_t)(kb + kr) * DHEAD + ko];
                int vr = c >> 2, vo = (c & 3) * 8;
                *(f32x4*)&Vs[vr * 40 + vo] = *(const f32x4*)&Vb[(size_t)vr * S_LEN + kb + vo];
            }
            __syncthreads();

            if (kb <= qw + 15) {   // wave-uniform causal skip
                f32x4 sc[2] = {};
                #pragma unroll
                for (int t = 0; t < 2; ++t)
                    #pragma unroll
                    for (int dc = 0; dc < 4; ++dc) {
                        bf16x8 kf = *(const bf16x8*)&Ks[(t * 16 + col) * 136 + dc * 32 + quad * 8];
                        sc[t] = __builtin_amdgcn_mfma_f32_16x16x32_bf16(qf[dc], kf, sc[t], 0, 0, 0);
                    }

                float pv[2][4], alpha[4];
                #pragma unroll
                for (int r = 0; r < 4; ++r) {
                    int q_g = qw + quad * 4 + r;
                    float s0 = sc[0][r] * scale;
                    float s1 = sc[1][r] * scale;
                    if (kb + col > q_g)      s0 = -1e30f;
                    if (kb + 16 + col > q_g) s1 = -1e30f;
                    float mx = fmaxf(s0, s1);
                    mx = fmaxf(mx, __shfl_xor(mx, 1));
                    mx = fmaxf(mx, __shfl_xor(mx, 2));
                    mx = fmaxf(mx, __shfl_xor(mx, 4));
                    mx = fmaxf(mx, __shfl_xor(mx, 8));
                    float mn = fmaxf(mrow[r], mx);
                    float al = __expf(mrow[r] - mn);
                    float p0 = __expf(s0 - mn);
                    float p1 = __expf(s1 - mn);
                    float rs = p0 + p1;
                    rs += __shfl_xor(rs, 1);
                    rs += __shfl_xor(rs, 2);
                    rs += __shfl_xor(rs, 4);
                    rs += __shfl_xor(rs, 8);
                    lrow[r] = lrow[r] * al + rs;
                    mrow[r] = mn;
                    alpha[r] = al;
                    pv[0][r] = p0; pv[1][r] = p1;
                }
                #pragma unroll
                for (int ni = 0; ni < 8; ++ni)
                    #pragma unroll
                    for (int r = 0; r < 4; ++r)
                        accO[ni][r] *= alpha[r];

                u16* P = Ps[wave];
                #pragma unroll
                for (int t = 0; t < 2; ++t)
                    #pragma unroll
                    for (int r = 0; r < 4; ++r)
                        P[(quad * 4 + r) * 40 + t * 16 + col] = f2bf(pv[t][r]);
                asm volatile("s_waitcnt lgkmcnt(0)" ::: "memory");
                bf16x8 pf = *(const bf16x8*)&P[col * 40 + quad * 8];

                #pragma unroll
                for (int ni = 0; ni < 8; ++ni) {
                    bf16x8 vf = *(const bf16x8*)&Vs[(ni * 16 + col) * 40 + quad * 8];
                    accO[ni] = __builtin_amdgcn_mfma_f32_16x16x32_bf16(pf, vf, accO[ni], 0, 0, 0);
                }
            }
            __syncthreads();
        }

        #pragma unroll
        for (int ni = 0; ni < 8; ++ni)
            #pragma unroll
            for (int r = 0; r < 4; ++r) {
                int q_g = qw + quad * 4 + r;
                int d = ni * 16 + col;
                float v = accO[ni][r] / lrow[r];
                Ao[((size_t)(b * S_LEN + q_g)) * DMODEL + h * DHEAD + d] = f2bf(v);
            }
    }
}

extern "C" void kernel_launch(void* const* d_in, const int* in_sizes, int n_in,
                              void* d_out, int out_size, void* d_ws, size_t ws_size,
                              hipStream_t stream) {
    const float* x    = (const float*)d_in[0];
    const float* cosT = (const float*)d_in[1];
    const float* sinT = (const float*)d_in[2];
    const float* Wq   = (const float*)d_in[3];
    const float* Wk   = (const float*)d_in[4];
    const float* Wv   = (const float*)d_in[5];
    const float* Wo   = (const float*)d_in[6];

    char* ws = (char*)d_ws;
    size_t off = 0;
    auto carve = [&](size_t bytes) {
        void* p = ws + off;
        off += (bytes + 255) & ~(size_t)255;
        return p;
    };
    const size_t xN = (size_t)BATCH * S_LEN * DMODEL;      // 8388608
    const size_t wN = (size_t)DMODEL * DMODEL;             // 4194304
    u16* xb  = (u16*)carve(xN * 2);
    u16* wqb = (u16*)carve(wN * 2);
    u16* wkb = (u16*)carve(wN * 2);
    u16* wvb = (u16*)carve(wN * 2);
    u16* wob = (u16*)carve(wN * 2);
    u16* Qb  = (u16*)carve(xN * 2);
    u16* Kb  = (u16*)carve(xN * 2);
    u16* Vtb = (u16*)carve(xN * 2);
    u16* attn = xb;   // alias: xb dead after V projection; attention writes after.

    cvt_bf16<<<(int)(xN / 4 / 256), 256, 0, stream>>>(x,  xb,  (int)(xN / 4));
    cvt_bf16<<<(int)(wN / 4 / 256), 256, 0, stream>>>(Wq, wqb, (int)(wN / 4));
    cvt_bf16<<<(int)(wN / 4 / 256), 256, 0, stream>>>(Wk, wkb, (int)(wN / 4));
    cvt_bf16<<<(int)(wN / 4 / 256), 256, 0, stream>>>(Wv, wvb, (int)(wN / 4));
    cvt_bf16<<<(int)(wN / 4 / 256), 256, 0, stream>>>(Wo, wob, (int)(wN / 4));

    const int M = BATCH * S_LEN;   // 4096
    dim3 ggrid(DMODEL / 128, M / 128);   // (16, 32)
    gemm_bt<1><<<ggrid, 256, 0, stream>>>(xb, wqb, Qb,  M, DMODEL, DMODEL);
    gemm_bt<1><<<ggrid, 256, 0, stream>>>(xb, wkb, Kb,  M, DMODEL, DMODEL);
    gemm_bt<2><<<ggrid, 256, 0, stream>>>(xb, wvb, Vtb, M, DMODEL, DMODEL);

    rope_kernel<<<dim3(S_LEN * 64 / 256, BATCH * NHEADS, 2), 256, 0, stream>>>(Qb, Kb, cosT, sinT);

    attn_kernel<<<dim3(512, 1), 256, 0, stream>>>(Qb, Kb, Vtb, attn);

    gemm_bt<3><<<ggrid, 256, 0, stream>>>(attn, wob, d_out, M, DMODEL, DMODEL);
}

// Round 3
// 441.901 us; speedup vs baseline: 1.5325x; 1.1737x over previous
//
#include <hip/hip_runtime.h>

#define S_LEN 2048
#define DMODEL 2048
#define NHEADS 16
#define DHEAD 128
#define BATCH 2

typedef unsigned short u16;
typedef __attribute__((ext_vector_type(8))) __bf16 bf16x8;
typedef __attribute__((ext_vector_type(4))) float f32x4;

// RNE convert (used in GEMM epilogues / rope — amortized)
__device__ __forceinline__ u16 f2bf(float f) {
    union { float f; unsigned int u; } a; a.f = f;
    unsigned int u = a.u;
    u += 0x7fffu + ((u >> 16) & 1u);
    return (u16)(u >> 16);
}
// cheap round-half-up convert (attn inner loop)
__device__ __forceinline__ u16 f2bf_fast(float f) {
    union { float f; unsigned int u; } a; a.f = f;
    return (u16)((a.u + 0x8000u) >> 16);
}
__device__ __forceinline__ float bf2f(u16 b) {
    union { unsigned int u; float f; } a; a.u = ((unsigned int)b) << 16;
    return a.f;
}

// async global->LDS, 16B per lane; lds base wave-uniform (lane scatter = +lane*16)
__device__ __forceinline__ void g2l16(const void* g, void* l) {
    __builtin_amdgcn_global_load_lds((const __attribute__((address_space(1))) unsigned int*)g,
                                     (__attribute__((address_space(3))) unsigned int*)l,
                                     16, 0, 0);
}

// ---------------- fp32 -> bf16 converts ----------------
__global__ void cvt_bf16(const float* __restrict__ in, u16* __restrict__ out, int n4) {
    int i = blockIdx.x * 256 + threadIdx.x;
    if (i >= n4) return;
    f32x4 v = *(const f32x4*)(in + (size_t)i * 4);
    ushort4 o;
    o.x = f2bf(v[0]); o.y = f2bf(v[1]); o.z = f2bf(v[2]); o.w = f2bf(v[3]);
    *(ushort4*)(out + (size_t)i * 4) = o;
}

// 4 weights in one launch; dst slices contiguous (Wq|Wk|Wv|Wo)
__global__ void cvt_w4(const float* __restrict__ w0, const float* __restrict__ w1,
                       const float* __restrict__ w2, const float* __restrict__ w3,
                       u16* __restrict__ dst, int n4) {
    int y = blockIdx.y;
    const float* src = (y == 0) ? w0 : (y == 1) ? w1 : (y == 2) ? w2 : w3;
    u16* out = dst + (size_t)y * DMODEL * DMODEL;
    int i = blockIdx.x * 256 + threadIdx.x;
    if (i >= n4) return;
    f32x4 v = *(const f32x4*)(src + (size_t)i * 4);
    ushort4 o;
    o.x = f2bf(v[0]); o.y = f2bf(v[1]); o.z = f2bf(v[2]); o.w = f2bf(v[3]);
    *(ushort4*)(out + (size_t)i * 4) = o;
}

// ---------------- RoPE in-place on Q and K, (B,H,S,Dh) ----------------
// Q additionally pre-scaled by 1/sqrt(Dh) * log2(e) so attn softmax runs in exp2 domain.
#define QK_PRESCALE 0.12751744f
__global__ void rope_kernel(u16* __restrict__ Q, u16* __restrict__ K,
                            const float* __restrict__ cosT, const float* __restrict__ sinT) {
    u16* T = blockIdx.z ? K : Q;
    const float pre = blockIdx.z ? 1.0f : QK_PRESCALE;
    int bh = blockIdx.y;
    int t = blockIdx.x * 256 + threadIdx.x;
    int s = t >> 6;
    int d = t & 63;
    u16* row = T + ((size_t)bh * S_LEN + s) * DHEAD;
    float c  = cosT[s * DHEAD + d];
    float sn = sinT[s * DHEAD + d];
    float q1 = bf2f(row[d]);
    float q2 = bf2f(row[d + 64]);
    row[d]      = f2bf((q1 * c - q2 * sn) * pre);
    row[d + 64] = f2bf((q2 * c + q1 * sn) * pre);
}

// ---------------- fused QKV GEMM: C(4096,6144) = A(4096,2048) * Wqkv(6144,2048)^T ----
// n-slice 0: Q -> (B,H,S,Dh); slice 1: K -> (B,H,S,Dh); slice 2: V -> (B,H,Dh,S) packed.
__global__ __launch_bounds__(256) void gemm_qkv(const u16* __restrict__ A,
                                                const u16* __restrict__ W,
                                                u16* __restrict__ Qo,
                                                u16* __restrict__ Ko,
                                                u16* __restrict__ Vto) {
    __shared__ u16 As[128 * 32];
    __shared__ u16 Ws[128 * 32];
    const int tid  = threadIdx.x;
    const int lane = tid & 63;
    const int wave = tid >> 6;
    const int wm = wave >> 1, wn = wave & 1;
    const int col = lane & 15, quad = lane >> 4;
    const int m0 = blockIdx.y * 128, n0 = blockIdx.x * 128;
    const int K = DMODEL;

    f32x4 acc[4][4] = {};

    for (int kk = 0; kk < K; kk += 32) {
        #pragma unroll
        for (int i = 0; i < 2; ++i) {
            int c = i * 256 + tid;
            int row = c >> 2, ko = (c & 3) * 8;
            int cb = i * 256 + wave * 64;
            g2l16(A + (size_t)(m0 + row) * K + kk + ko, (void*)(As + cb * 8));
            g2l16(W + (size_t)(n0 + row) * K + kk + ko, (void*)(Ws + cb * 8));
        }
        __syncthreads();
        bf16x8 af[4], wf[4];
        #pragma unroll
        for (int mi = 0; mi < 4; ++mi)
            af[mi] = *(const bf16x8*)&As[(wm * 64 + mi * 16 + col) * 32 + quad * 8];
        #pragma unroll
        for (int ni = 0; ni < 4; ++ni)
            wf[ni] = *(const bf16x8*)&Ws[(wn * 64 + ni * 16 + col) * 32 + quad * 8];
        #pragma unroll
        for (int mi = 0; mi < 4; ++mi)
            #pragma unroll
            for (int ni = 0; ni < 4; ++ni)
                acc[mi][ni] = __builtin_amdgcn_mfma_f32_16x16x32_bf16(af[mi], wf[ni], acc[mi][ni], 0, 0, 0);
        __syncthreads();
    }

    const int which = n0 >> 11;   // 0=Q, 1=K, 2=V (block-uniform)
    if (which == 2) {
        #pragma unroll
        for (int mi = 0; mi < 4; ++mi) {
            #pragma unroll
            for (int ni = 0; ni < 4; ++ni) {
                int s0   = m0 + wm * 64 + mi * 16 + quad * 4;
                int ncol = (n0 & 2047) + wn * 64 + ni * 16 + col;
                int b = s0 >> 11, s = s0 & 2047;
                int h = ncol >> 7, d = ncol & 127;
                ushort4 o;
                o.x = f2bf(acc[mi][ni][0]); o.y = f2bf(acc[mi][ni][1]);
                o.z = f2bf(acc[mi][ni][2]); o.w = f2bf(acc[mi][ni][3]);
                *(ushort4*)&Vto[(((size_t)(b * NHEADS + h)) * DHEAD + d) * S_LEN + s] = o;
            }
        }
    } else {
        u16* out = which ? Ko : Qo;
        #pragma unroll
        for (int mi = 0; mi < 4; ++mi)
            #pragma unroll
            for (int ni = 0; ni < 4; ++ni)
                #pragma unroll
                for (int r = 0; r < 4; ++r) {
                    int row  = m0 + wm * 64 + mi * 16 + quad * 4 + r;
                    int ncol = (n0 & 2047) + wn * 64 + ni * 16 + col;
                    int b = row >> 11, s = row & 2047;
                    int h = ncol >> 7, d = ncol & 127;
                    out[(((size_t)(b * NHEADS + h)) * S_LEN + s) * DHEAD + d] = f2bf(acc[mi][ni][r]);
                }
    }
}

// ---------------- output GEMM: out(4096,2048) fp32 = A(4096,2048) * Wo(2048,2048)^T ----
__global__ __launch_bounds__(256) void gemm_out(const u16* __restrict__ A,
                                                const u16* __restrict__ W,
                                                float* __restrict__ out) {
    __shared__ u16 As[128 * 32];
    __shared__ u16 Ws[128 * 32];
    const int tid  = threadIdx.x;
    const int lane = tid & 63;
    const int wave = tid >> 6;
    const int wm = wave >> 1, wn = wave & 1;
    const int col = lane & 15, quad = lane >> 4;
    const int m0 = blockIdx.y * 128, n0 = blockIdx.x * 128;
    const int K = DMODEL;

    f32x4 acc[4][4] = {};

    for (int kk = 0; kk < K; kk += 32) {
        #pragma unroll
        for (int i = 0; i < 2; ++i) {
            int c = i * 256 + tid;
            int row = c >> 2, ko = (c & 3) * 8;
            int cb = i * 256 + wave * 64;
            g2l16(A + (size_t)(m0 + row) * K + kk + ko, (void*)(As + cb * 8));
            g2l16(W + (size_t)(n0 + row) * K + kk + ko, (void*)(Ws + cb * 8));
        }
        __syncthreads();
        bf16x8 af[4], wf[4];
        #pragma unroll
        for (int mi = 0; mi < 4; ++mi)
            af[mi] = *(const bf16x8*)&As[(wm * 64 + mi * 16 + col) * 32 + quad * 8];
        #pragma unroll
        for (int ni = 0; ni < 4; ++ni)
            wf[ni] = *(const bf16x8*)&Ws[(wn * 64 + ni * 16 + col) * 32 + quad * 8];
        #pragma unroll
        for (int mi = 0; mi < 4; ++mi)
            #pragma unroll
            for (int ni = 0; ni < 4; ++ni)
                acc[mi][ni] = __builtin_amdgcn_mfma_f32_16x16x32_bf16(af[mi], wf[ni], acc[mi][ni], 0, 0, 0);
        __syncthreads();
    }

    #pragma unroll
    for (int mi = 0; mi < 4; ++mi)
        #pragma unroll
        for (int ni = 0; ni < 4; ++ni)
            #pragma unroll
            for (int r = 0; r < 4; ++r) {
                int row  = m0 + wm * 64 + mi * 16 + quad * 4 + r;
                int ncol = n0 + wn * 64 + ni * 16 + col;
                out[(size_t)row * DMODEL + ncol] = acc[mi][ni][r];
            }
}

// ---------------- causal flash attention (transposed-score softmax) ----------------
// Q (pre-scaled),K: (B,H,S,Dh) bf16. Vt: (B,H,Dh,S) bf16. Out: (B,S,H*Dh) bf16.
// Scores computed transposed (S^T = K*Q^T, operand swap): each lane owns one q-row
// (q = lane&15) -> softmax reductions are 2 shfl_xor instead of 8, m/l scalar per lane.
// Grid 1024: one 64-row q-tile per block, heavy tiles dispatched first;
// blockIdx&7 clusters 4 heads per XCD for L2 locality.
__global__ __launch_bounds__(256) void attn_kernel(const u16* __restrict__ Q,
                                                   const u16* __restrict__ K,
                                                   const u16* __restrict__ Vt,
                                                   u16* __restrict__ Ao) {
    __shared__ u16 Ks[32 * 136];
    __shared__ u16 Vs[128 * 40];
    __shared__ u16 Ps[4][16 * 40];

    const int tid  = threadIdx.x;
    const int lane = tid & 63;
    const int wave = tid >> 6;
    const int col = lane & 15, quad = lane >> 4;
    const int xcd = blockIdx.x & 7;
    const int sub = (blockIdx.x >> 3) & 3;
    const int bh  = xcd * 4 + sub;            // 4 heads per XCD
    const int qtile = 31 - (int)(blockIdx.x >> 5);  // heavy first
    const int b = bh >> 4, h = bh & 15;
    const int qb = qtile * 64;
    const int qw = qb + wave * 16;

    const u16* Qb = Q  + (size_t)bh * S_LEN * DHEAD;
    const u16* Kb = K  + (size_t)bh * S_LEN * DHEAD;
    const u16* Vb = Vt + (size_t)bh * DHEAD * S_LEN;

    bf16x8 qf[4];
    #pragma unroll
    for (int dc = 0; dc < 4; ++dc)
        qf[dc] = *(const bf16x8*)&Qb[(size_t)(qw + col) * DHEAD + dc * 32 + quad * 8];

    f32x4 accO[8] = {};
    float mrow = -1e30f, lrow = 0.0f;   // state for q-row (qw + col), replicated across quads

    const int kend = qb + 64;
    for (int kb = 0; kb < kend; kb += 32) {
        #pragma unroll
        for (int i = 0; i < 2; ++i) {
            int c = tid + i * 256;
            int kr = c >> 4, ko = (c & 15) * 8;
            *(f32x4*)&Ks[kr * 136 + ko] = *(const f32x4*)&Kb[(size_t)(kb + kr) * DHEAD + ko];
            int vr = c >> 2, vo = (c & 3) * 8;
            *(f32x4*)&Vs[vr * 40 + vo] = *(const f32x4*)&Vb[(size_t)vr * S_LEN + kb + vo];
        }
        __syncthreads();

        if (kb <= qw + 15) {   // wave-uniform causal skip
            // S^T tiles: D[m=key][n=q] via operand swap (A=K-frag, B=Q-frag)
            f32x4 sc[2] = {};
            #pragma unroll
            for (int t = 0; t < 2; ++t)
                #pragma unroll
                for (int dc = 0; dc < 4; ++dc) {
                    bf16x8 kf = *(const bf16x8*)&Ks[(t * 16 + col) * 136 + dc * 32 + quad * 8];
                    sc[t] = __builtin_amdgcn_mfma_f32_16x16x32_bf16(kf, qf[dc], sc[t], 0, 0, 0);
                }

            const int q_g = qw + col;
            float sv[2][4];
            #pragma unroll
            for (int t = 0; t < 2; ++t)
                #pragma unroll
                for (int r = 0; r < 4; ++r) {
                    int k_g = kb + t * 16 + quad * 4 + r;
                    sv[t][r] = (k_g <= q_g) ? sc[t][r] : -1e30f;
                }

            // per-lane local max over 8, then across quads (lanes col, col+16, col+32, col+48)
            float m01 = fmaxf(fmaxf(sv[0][0], sv[0][1]), fmaxf(sv[0][2], sv[0][3]));
            float m23 = fmaxf(fmaxf(sv[1][0], sv[1][1]), fmaxf(sv[1][2], sv[1][3]));
            float mloc = fmaxf(m01, m23);
            mloc = fmaxf(mloc, __shfl_xor(mloc, 16));
            mloc = fmaxf(mloc, __shfl_xor(mloc, 32));
            float mn = fmaxf(mrow, mloc);
            float al = exp2f(mrow - mn);

            float p[2][4], rloc = 0.0f;
            #pragma unroll
            for (int t = 0; t < 2; ++t)
                #pragma unroll
                for (int r = 0; r < 4; ++r) {
                    p[t][r] = exp2f(sv[t][r] - mn);
                    rloc += p[t][r];
                }
            rloc += __shfl_xor(rloc, 16);
            rloc += __shfl_xor(rloc, 32);
            lrow = lrow * al + rloc;
            mrow = mn;

            if (__any(al != 1.0f)) {   // rescale only when a max moved (rare after warmup)
                float alb[4];
                #pragma unroll
                for (int r = 0; r < 4; ++r)
                    alb[r] = __shfl(al, quad * 4 + r);   // alpha for acc row quad*4+r
                #pragma unroll
                for (int ni = 0; ni < 8; ++ni)
                    #pragma unroll
                    for (int r = 0; r < 4; ++r)
                        accO[ni][r] *= alb[r];
            }

            // P[q][key] to LDS (A-layout for PV); lane owns q=col, keys t*16+quad*4+r
            u16* P = Ps[wave];
            #pragma unroll
            for (int t = 0; t < 2; ++t) {
                ushort4 o;
                o.x = f2bf_fast(p[t][0]); o.y = f2bf_fast(p[t][1]);
                o.z = f2bf_fast(p[t][2]); o.w = f2bf_fast(p[t][3]);
                *(ushort4*)&P[col * 40 + t * 16 + quad * 4] = o;
            }
            asm volatile("s_waitcnt lgkmcnt(0)" ::: "memory");
            bf16x8 pf = *(const bf16x8*)&P[col * 40 + quad * 8];

            #pragma unroll
            for (int ni = 0; ni < 8; ++ni) {
                bf16x8 vf = *(const bf16x8*)&Vs[(ni * 16 + col) * 40 + quad * 8];
                accO[ni] = __builtin_amdgcn_mfma_f32_16x16x32_bf16(pf, vf, accO[ni], 0, 0, 0);
            }
        }
        __syncthreads();
    }

    // epilogue: O / l (l lives in lane col==row), write (B,S,H*Dh) bf16
    float lb[4];
    #pragma unroll
    for (int r = 0; r < 4; ++r)
        lb[r] = 1.0f / __shfl(lrow, quad * 4 + r);
    #pragma unroll
    for (int ni = 0; ni < 8; ++ni)
        #pragma unroll
        for (int r = 0; r < 4; ++r) {
            int q_g = qw + quad * 4 + r;
            int d = ni * 16 + col;
            Ao[((size_t)(b * S_LEN + q_g)) * DMODEL + h * DHEAD + d] = f2bf(accO[ni][r] * lb[r]);
        }
}

extern "C" void kernel_launch(void* const* d_in, const int* in_sizes, int n_in,
                              void* d_out, int out_size, void* d_ws, size_t ws_size,
                              hipStream_t stream) {
    const float* x    = (const float*)d_in[0];
    const float* cosT = (const float*)d_in[1];
    const float* sinT = (const float*)d_in[2];
    const float* Wq   = (const float*)d_in[3];
    const float* Wk   = (const float*)d_in[4];
    const float* Wv   = (const float*)d_in[5];
    const float* Wo   = (const float*)d_in[6];

    char* ws = (char*)d_ws;
    size_t off = 0;
    auto carve = [&](size_t bytes) {
        void* p = ws + off;
        off += (bytes + 255) & ~(size_t)255;
        return p;
    };
    const size_t xN = (size_t)BATCH * S_LEN * DMODEL;      // 8388608
    const size_t wN = (size_t)DMODEL * DMODEL;             // 4194304
    u16* xb   = (u16*)carve(xN * 2);
    u16* wqkv = (u16*)carve(wN * 2 * 4);   // Wq | Wk | Wv | Wo contiguous
    u16* wob  = wqkv + wN * 3;
    u16* Qb   = (u16*)carve(xN * 2);
    u16* Kb   = (u16*)carve(xN * 2);
    u16* Vtb  = (u16*)carve(xN * 2);
    u16* attn = xb;   // alias: xb dead after QKV GEMM; attention writes after.

    cvt_bf16<<<(int)(xN / 4 / 256), 256, 0, stream>>>(x, xb, (int)(xN / 4));
    cvt_w4<<<dim3((int)(wN / 4 / 256), 4), 256, 0, stream>>>(Wq, Wk, Wv, Wo, wqkv, (int)(wN / 4));

    gemm_qkv<<<dim3(48, 32), 256, 0, stream>>>(xb, wqkv, Qb, Kb, Vtb);

    rope_kernel<<<dim3(S_LEN * 64 / 256, BATCH * NHEADS, 2), 256, 0, stream>>>(Qb, Kb, cosT, sinT);

    attn_kernel<<<dim3(1024), 256, 0, stream>>>(Qb, Kb, Vtb, attn);

    gemm_out<<<dim3(16, 32), 256, 0, stream>>>(attn, wob, (float*)d_out);
}